// Round 10
// baseline (68456.433 us; speedup 1.0000x reference)
//
#include <hip/hip_runtime.h>

typedef unsigned short u16;
typedef __attribute__((ext_vector_type(8))) short short8;
typedef __attribute__((ext_vector_type(4))) short short4v;
typedef __attribute__((ext_vector_type(4))) float f32x4;

#define NB 256      // batch
#define TE 512      // encoder T
#define DK 256      // key dim
#define DV 256      // value dim
#define HH 512      // hidden
#define NV 35       // vocab
#define STEPS 300
#define TLEN 301
#define K1 1280     // LSTM1 inner dim: emb(512) + ctx(256) + h1(512)
#define K2 768      // LSTM2 inner dim: h1(512) + h2(256)
#define NBLK 256

__device__ __forceinline__ float bf2f(u16 u){ return __uint_as_float(((unsigned)u)<<16); }
__device__ __forceinline__ u16 f2bf(float f){
  unsigned u = __float_as_uint(f);
  u += 0x7fffu + ((u>>16)&1u);   // RNE
  return (u16)(u>>16);
}
__device__ __forceinline__ void splitbf(float f, short& hi, short& lo){
  u16 h = f2bf(f);
  float r = f - bf2f(h);
  hi = (short)h; lo = (short)f2bf(r);
}
__device__ __forceinline__ float sigm(float x){ return 1.f/(1.f+expf(-x)); }

// Hierarchical grid barrier: 8 per-XCD arrival counters (256B apart) + root.
// Flat single-counter version serialized 256 RMWs on one LLC line (~40us);
// this does 32 parallel RMWs per XCD line (~5us) + 8 root RMWs.
// Monotonic rounds; release on arrive, acquire on spin; threadfences for
// cross-XCD visibility (same ordering pattern as the R9-verified barrier).
__device__ __forceinline__ void gbar(unsigned* cnt, int b, unsigned round){
  __syncthreads();
  if (threadIdx.x == 0){
    __threadfence();
    unsigned* g    = cnt + (b&7)*64;     // per-XCD line (round-robin dispatch)
    unsigned* root = cnt + 8*64;
    __hip_atomic_fetch_add(g, 1u, __ATOMIC_RELEASE, __HIP_MEMORY_SCOPE_AGENT);
    if (b < 8){   // one leader per XCD group
      while (__hip_atomic_load(g, __ATOMIC_ACQUIRE, __HIP_MEMORY_SCOPE_AGENT) < round*32u)
        __builtin_amdgcn_s_sleep(1);
      __hip_atomic_fetch_add(root, 1u, __ATOMIC_RELEASE, __HIP_MEMORY_SCOPE_AGENT);
    }
    while (__hip_atomic_load(root, __ATOMIC_ACQUIRE, __HIP_MEMORY_SCOPE_AGENT) < round*8u)
      __builtin_amdgcn_s_sleep(2);
    __threadfence();
  }
  __syncthreads();
}

// ---------------- conversion kernel (once per launch) ----------------
__global__ void conv_cat_split(u16* __restrict__ dhi, u16* __restrict__ dlo,
                               const float* __restrict__ s1, const float* __restrict__ s2,
                               int k1, int k2, int total8){
  int i = blockIdx.x*blockDim.x + threadIdx.x;
  if (i >= total8) return;
  int ktot = k1 + k2;
  long e = (long)i*8;
  int r = (int)(e / ktot); int k = (int)(e - (long)r*ktot);
  const float* s = (k < k1) ? (s1 + (size_t)r*k1 + k) : (s2 + (size_t)r*k2 + (k-k1));
  short8 oh, ol;
  #pragma unroll
  for (int q=0;q<8;++q){ short h,l; splitbf(s[q],h,l); oh[q]=h; ol[q]=l; }
  *(short8*)(dhi + e) = oh;
  *(short8*)(dlo + e) = ol;
}

struct Params {
  const float *enc_key, *enc_val;
  const int *text, *lens;
  const float *emb;
  const u16 *W1h, *W1l, *W2h, *W2l;
  const float *bi1, *bh1, *bi2, *bh2;
  const float *Wout, *bout;
  float *h1b, *h2b, *ctx, *out;
  unsigned *cnt;
};

// ============ persistent cooperative kernel: all 300 steps ============
__global__ __launch_bounds__(512, 1) void decoder_k(Params P)
{
  __shared__ __align__(16) u16 AhS[2][2][4][16][8], AlS[2][2][4][16][8];
  __shared__ __align__(16) u16 BhS[2][4][4][16][8], BlS[2][4][4][16][8];
  __shared__ float gex[4][32][16];
  __shared__ float h2s[DK];
  __shared__ float e_s[TE];
  __shared__ float ctx_s[DV];
  __shared__ float ctxp[8][DV];
  __shared__ float red_s[16];

  const int b = blockIdx.x, tid = threadIdx.x;
  const int w = tid>>6, lane = tid&63;
  const int nh = w&1, gw = w>>1;
  const bool isA = tid < 256;
  const int an = tid>>3, akq = tid&7;
  const int jl  = (tid-256)>>2;
  const int koB = ((tid-256)&3)*8;
  const int gs = (jl>>4)&3, jhl = jl&15;
  const int en = tid>>4, ej = tid&15;

  const int jh0_1 = ((b&7)*4 + ((b>>3)&3))*16;
  const int n0_1  = (b>>5)*32;
  const int jh0_2 = ((b&7)*2 + ((b>>3)&1))*16;
  const int n0_2  = (b>>4)*32;
  const bool p2act = b < 128;

  float b1i = P.bi1[jh0_1+ej]      + P.bh1[jh0_1+ej];
  float b1f = P.bi1[HH+jh0_1+ej]   + P.bh1[HH+jh0_1+ej];
  float b1g = P.bi1[2*HH+jh0_1+ej] + P.bh1[2*HH+jh0_1+ej];
  float b1o = P.bi1[3*HH+jh0_1+ej] + P.bh1[3*HH+jh0_1+ej];
  float b2i=0.f,b2f=0.f,b2g=0.f,b2o=0.f;
  if (p2act){
    b2i = P.bi2[jh0_2+ej]      + P.bh2[jh0_2+ej];
    b2f = P.bi2[DK+jh0_2+ej]   + P.bh2[DK+jh0_2+ej];
    b2g = P.bi2[2*DK+jh0_2+ej] + P.bh2[2*DK+jh0_2+ej];
    b2o = P.bi2[3*DK+jh0_2+ej] + P.bh2[3*DK+jh0_2+ej];
  }
  const u16* pB1h = P.W1h + (size_t)(gs*512 + jh0_1 + jhl)*K1 + koB;
  const u16* pB1l = P.W1l + (size_t)(gs*512 + jh0_1 + jhl)*K1 + koB;
  const u16* pB2h = P.W2h + (size_t)(gs*256 + jh0_2 + jhl)*K2 + koB;
  const u16* pB2l = P.W2l + (size_t)(gs*256 + jh0_2 + jhl)*K2 + koB;

  float c1r = 0.f, c2r = 0.f;       // cell state in registers (1 cell/thread)
  unsigned round = 0;

  for (int t=0; t<STEPS; ++t){
    const int par = t&1;
    const float* h1_old = P.h1b + (size_t)par*NB*HH;
    float*       h1_new = P.h1b + (size_t)(par^1)*NB*HH;
    const float* h2_old = P.h2b + (size_t)par*NB*DK;
    float*       h2_new = P.h2b + (size_t)(par^1)*NB*DK;

    // ===================== phase 1: LSTM1 =====================
    {
      const float* aemb = nullptr; const float* actx = nullptr; const float* ah1 = nullptr;
      if (isA){
        int arow = n0_1 + an;
        aemb = P.emb + (size_t)P.text[arow*TLEN + t]*HH;
        actx = P.ctx + (size_t)arow*DV;
        ah1  = h1_old + (size_t)arow*HH;
      }
      f32x4 acc = {0.f,0.f,0.f,0.f};
      float4 av; short8 rbh, rbl;
      if (isA){
        int k = akq*4;
        const float* src = (k<512)? (aemb+k) : (k<768)? (actx+(k-512)) : (ah1+(k-768));
        av = *(const float4*)src;
      } else {
        rbh = *(const short8*)pB1h;
        rbl = *(const short8*)pB1l;
      }
      int cur = 0;
      for (int k0=0; k0<K1; k0+=32){
        if (isA){
          short4v hv, lv; short h,l;
          splitbf(av.x,h,l); hv[0]=h; lv[0]=l;
          splitbf(av.y,h,l); hv[1]=h; lv[1]=l;
          splitbf(av.z,h,l); hv[2]=h; lv[2]=l;
          splitbf(av.w,h,l); hv[3]=h; lv[3]=l;
          *(short4v*)&AhS[cur][an>>4][akq>>1][an&15][(akq&1)*4] = hv;
          *(short4v*)&AlS[cur][an>>4][akq>>1][an&15][(akq&1)*4] = lv;
          if (k0+32 < K1){
            int k = k0+32+akq*4;
            const float* src = (k<512)? (aemb+k) : (k<768)? (actx+(k-512)) : (ah1+(k-768));
            av = *(const float4*)src;
          }
        } else {
          *(short8*)&BhS[cur][gs][koB>>3][jhl][0] = rbh;
          *(short8*)&BlS[cur][gs][koB>>3][jhl][0] = rbl;
          if (k0+32 < K1){
            rbh = *(const short8*)(pB1h + k0+32);
            rbl = *(const short8*)(pB1l + k0+32);
          }
        }
        __syncthreads();
        short8 afh = *(const short8*)&AhS[cur][nh][lane>>4][lane&15][0];
        short8 afl = *(const short8*)&AlS[cur][nh][lane>>4][lane&15][0];
        short8 bfh = *(const short8*)&BhS[cur][gw][lane>>4][lane&15][0];
        short8 bfl = *(const short8*)&BlS[cur][gw][lane>>4][lane&15][0];
        acc = __builtin_amdgcn_mfma_f32_16x16x32_bf16(afh, bfh, acc, 0,0,0);
        acc = __builtin_amdgcn_mfma_f32_16x16x32_bf16(afl, bfh, acc, 0,0,0);
        acc = __builtin_amdgcn_mfma_f32_16x16x32_bf16(afh, bfl, acc, 0,0,0);
        cur ^= 1;
      }
      #pragma unroll
      for (int r=0;r<4;++r) gex[gw][nh*16 + (lane>>4)*4 + r][lane&15] = acc[r];
      __syncthreads();
      {
        float iv = sigm(gex[0][en][ej] + b1i);
        float fv = sigm(gex[1][en][ej] + b1f);
        float gv = tanhf(gex[2][en][ej] + b1g);
        float ov = sigm(gex[3][en][ej] + b1o);
        float cn = fv*c1r + iv*gv;
        c1r = cn;
        h1_new[(size_t)(n0_1+en)*HH + jh0_1+ej] = ov*tanhf(cn);
      }
    }
    ++round; gbar(P.cnt, b, round);

    // ===================== phase 2: LSTM2 (blocks < 128) =====================
    if (p2act){
      const float* ah1 = nullptr; const float* ah2 = nullptr;
      if (isA){
        ah1 = h1_new + (size_t)(n0_2+an)*HH;
        ah2 = h2_old + (size_t)(n0_2+an)*DK;
      }
      f32x4 acc = {0.f,0.f,0.f,0.f};
      float4 av; short8 rbh, rbl;
      if (isA){
        int k = akq*4;
        const float* src = (k<512)? (ah1+k) : (ah2+(k-512));
        av = *(const float4*)src;
      } else {
        rbh = *(const short8*)pB2h;
        rbl = *(const short8*)pB2l;
      }
      int cur = 0;
      for (int k0=0; k0<K2; k0+=32){
        if (isA){
          short4v hv, lv; short h,l;
          splitbf(av.x,h,l); hv[0]=h; lv[0]=l;
          splitbf(av.y,h,l); hv[1]=h; lv[1]=l;
          splitbf(av.z,h,l); hv[2]=h; lv[2]=l;
          splitbf(av.w,h,l); hv[3]=h; lv[3]=l;
          *(short4v*)&AhS[cur][an>>4][akq>>1][an&15][(akq&1)*4] = hv;
          *(short4v*)&AlS[cur][an>>4][akq>>1][an&15][(akq&1)*4] = lv;
          if (k0+32 < K2){
            int k = k0+32+akq*4;
            const float* src = (k<512)? (ah1+k) : (ah2+(k-512));
            av = *(const float4*)src;
          }
        } else {
          *(short8*)&BhS[cur][gs][koB>>3][jhl][0] = rbh;
          *(short8*)&BlS[cur][gs][koB>>3][jhl][0] = rbl;
          if (k0+32 < K2){
            rbh = *(const short8*)(pB2h + k0+32);
            rbl = *(const short8*)(pB2l + k0+32);
          }
        }
        __syncthreads();
        short8 afh = *(const short8*)&AhS[cur][nh][lane>>4][lane&15][0];
        short8 afl = *(const short8*)&AlS[cur][nh][lane>>4][lane&15][0];
        short8 bfh = *(const short8*)&BhS[cur][gw][lane>>4][lane&15][0];
        short8 bfl = *(const short8*)&BlS[cur][gw][lane>>4][lane&15][0];
        acc = __builtin_amdgcn_mfma_f32_16x16x32_bf16(afh, bfh, acc, 0,0,0);
        acc = __builtin_amdgcn_mfma_f32_16x16x32_bf16(afl, bfh, acc, 0,0,0);
        acc = __builtin_amdgcn_mfma_f32_16x16x32_bf16(afh, bfl, acc, 0,0,0);
        cur ^= 1;
      }
      #pragma unroll
      for (int r=0;r<4;++r) gex[gw][nh*16 + (lane>>4)*4 + r][lane&15] = acc[r];
      __syncthreads();
      {
        float iv = sigm(gex[0][en][ej] + b2i);
        float fv = sigm(gex[1][en][ej] + b2f);
        float gv = tanhf(gex[2][en][ej] + b2g);
        float ov = sigm(gex[3][en][ej] + b2o);
        float cn = fv*c2r + iv*gv;
        c2r = cn;
        h2_new[(size_t)(n0_2+en)*DK + jh0_2+ej] = ov*tanhf(cn);
      }
    }
    ++round; gbar(P.cnt, b, round);

    // ===================== phase 3: attention + output (row n = b) =====================
    {
      const int n = b;
      int L = P.lens[n] >> 3;
      if (tid < DK) h2s[tid] = h2_new[(size_t)n*DK + tid];
      __syncthreads();
      float qreg[32];
      {
        int off = (lane&7)*32;
        #pragma unroll
        for (int q=0;q<32;q+=4){
          float4 v4 = *(const float4*)&h2s[off+q];
          qreg[q]=v4.x; qreg[q+1]=v4.y; qreg[q+2]=v4.z; qreg[q+3]=v4.w;
        }
      }
      const float* kb = P.enc_key + (size_t)n*TE*DK;
      for (int r = w*8 + (lane>>3); r < L; r += 64){
        const float* kr = kb + (size_t)r*DK + (lane&7)*32;
        float s = 0.f;
        #pragma unroll
        for (int q=0;q<32;q+=4){
          float4 kv = *(const float4*)(kr + q);
          s += kv.x*qreg[q] + kv.y*qreg[q+1] + kv.z*qreg[q+2] + kv.w*qreg[q+3];
        }
        s += __shfl_xor(s,1); s += __shfl_xor(s,2); s += __shfl_xor(s,4);
        if ((lane&7)==0) e_s[r] = s;
      }
      __syncthreads();
      float v = (tid < L) ? e_s[tid] : -1e30f;
      float m = v;
      #pragma unroll
      for (int o=1;o<64;o<<=1) m = fmaxf(m, __shfl_xor(m,o));
      if (lane==0) red_s[w] = m;
      __syncthreads();
      m = red_s[0];
      #pragma unroll
      for (int q=1;q<8;++q) m = fmaxf(m, red_s[q]);
      float p = (tid < L) ? expf(v-m) : 0.f;
      float sm = p;
      #pragma unroll
      for (int o=1;o<64;o<<=1) sm += __shfl_xor(sm,o);
      if (lane==0) red_s[8+w] = sm;
      __syncthreads();
      sm = red_s[8];
      #pragma unroll
      for (int q=1;q<8;++q) sm += red_s[8+q];
      e_s[tid] = p * (1.f/sm);
      __syncthreads();
      float4 cacc = {0.f,0.f,0.f,0.f};
      const float* vpb = P.enc_val + (size_t)n*TE*DV + lane*4;
      for (int r = w; r < L; r += 8){
        float a = e_s[r];
        float4 vv4 = *(const float4*)(vpb + (size_t)r*DV);
        cacc.x += a*vv4.x; cacc.y += a*vv4.y; cacc.z += a*vv4.z; cacc.w += a*vv4.w;
      }
      *(float4*)&ctxp[w][lane*4] = cacc;
      __syncthreads();
      if (tid < DV){
        float cv = 0.f;
        #pragma unroll
        for (int q=0;q<8;++q) cv += ctxp[q][tid];
        ctx_s[tid] = cv;
        P.ctx[(size_t)n*DV + tid] = cv;
      }
      __syncthreads();
      #pragma unroll
      for (int vb2=0; vb2<2; ++vb2){
        int vvv = vb2*32 + (tid>>4);
        if (vvv < NV){
          int kbase = (tid&15)*32;
          float s = 0.f;
          #pragma unroll
          for (int q=0;q<32;q+=4){
            float4 w4 = *(const float4*)(P.Wout + (size_t)vvv*512 + kbase + q);
            int k = kbase + q;
            const float* xs = (k < DK)? &h2s[k] : &ctx_s[k-DK];
            s += w4.x*xs[0] + w4.y*xs[1] + w4.z*xs[2] + w4.w*xs[3];
          }
          s += __shfl_xor(s,1); s += __shfl_xor(s,2); s += __shfl_xor(s,4); s += __shfl_xor(s,8);
          if ((tid&15)==0) P.out[((size_t)n*STEPS + t)*NV + vvv] = s + P.bout[vvv];
        }
      }
    }
    ++round; gbar(P.cnt, b, round);
  }
}

// ---------------- host ----------------
extern "C" void kernel_launch(void* const* d_in, const int* in_sizes, int n_in,
                              void* d_out, int out_size, void* d_ws, size_t ws_size,
                              hipStream_t stream)
{
  const float* enc_key = (const float*)d_in[0];
  const float* enc_val = (const float*)d_in[1];
  const int*   text    = (const int*)d_in[2];
  const int*   lens    = (const int*)d_in[3];
  const float* emb     = (const float*)d_in[5];
  const float* W_ih1   = (const float*)d_in[6];
  const float* W_hh1   = (const float*)d_in[7];
  const float* b_ih1   = (const float*)d_in[8];
  const float* b_hh1   = (const float*)d_in[9];
  const float* W_ih2   = (const float*)d_in[10];
  const float* W_hh2   = (const float*)d_in[11];
  const float* b_ih2   = (const float*)d_in[12];
  const float* b_hh2   = (const float*)d_in[13];
  const float* W_out   = (const float*)d_in[14];
  const float* b_out   = (const float*)d_in[15];
  float* out = (float*)d_out;

  char* ws = (char*)d_ws;
  size_t off = 0;
  auto alloc = [&](size_t bytes)->char*{
    char* p = ws + off; off = (off + bytes + 255) & ~(size_t)255; return p;
  };

  u16* Wc1h = (u16*)alloc((size_t)2048*K1*2);
  u16* Wc1l = (u16*)alloc((size_t)2048*K1*2);
  u16* Wc2h = (u16*)alloc((size_t)1024*K2*2);
  u16* Wc2l = (u16*)alloc((size_t)1024*K2*2);
  float* h1b = (float*)alloc((size_t)2*NB*HH*4);
  float* h2b = (float*)alloc((size_t)2*NB*DK*4);
  float* ctx = (float*)alloc((size_t)NB*DV*4);
  unsigned* cnt = (unsigned*)alloc(4096);   // 8 group lines (256B apart) + root

  // zero recurrent state + barrier counters (contiguous h1b..cnt); runs each
  // graph replay before the cooperative kernel on the same stream.
  size_t zbytes = ((char*)cnt + 4096) - (char*)h1b;
  (void)hipMemsetAsync(h1b, 0, zbytes, stream);

  {
    int t8 = 2048*K1/8;
    conv_cat_split<<<(t8+255)/256, 256, 0, stream>>>(Wc1h, Wc1l, W_ih1, W_hh1, 768, 512, t8);
  }
  {
    int t8 = 1024*K2/8;
    conv_cat_split<<<(t8+255)/256, 256, 0, stream>>>(Wc2h, Wc2l, W_ih2, W_hh2, 512, 256, t8);
  }

  Params p;
  p.enc_key = enc_key; p.enc_val = enc_val;
  p.text = text; p.lens = lens; p.emb = emb;
  p.W1h = Wc1h; p.W1l = Wc1l; p.W2h = Wc2h; p.W2l = Wc2l;
  p.bi1 = b_ih1; p.bh1 = b_hh1; p.bi2 = b_ih2; p.bh2 = b_hh2;
  p.Wout = W_out; p.bout = b_out;
  p.h1b = h1b; p.h2b = h2b; p.ctx = ctx; p.out = out;
  p.cnt = cnt;

  void* kargs[] = { &p };
  (void)hipLaunchCooperativeKernel((void*)decoder_k, dim3(NBLK), dim3(512), kargs, 0, stream);
}

// Round 11
// 25631.702 us; speedup vs baseline: 2.6708x; 2.6708x over previous
//
#include <hip/hip_runtime.h>

typedef unsigned short u16;
typedef __attribute__((ext_vector_type(8))) short short8;
typedef __attribute__((ext_vector_type(4))) float f32x4;

#define NB 256      // batch
#define TE 512      // encoder T
#define DK 256      // key dim
#define DV 256      // value dim
#define HH 512      // hidden
#define NV 35       // vocab
#define STEPS 300
#define TLEN 301
#define K1 1280     // LSTM1 inner dim: emb(512) + ctx(256) + h1(512)
#define K2 768      // LSTM2 inner dim: h1(512) + h2(256)

__device__ __forceinline__ float bf2f(u16 u){ return __uint_as_float(((unsigned)u)<<16); }
__device__ __forceinline__ u16 f2bf(float f){
  unsigned u = __float_as_uint(f);
  u += 0x7fffu + ((u>>16)&1u);   // RNE
  return (u16)(u>>16);
}
__device__ __forceinline__ void splitbf(float f, short& hi, short& lo){
  u16 h = f2bf(f);
  float r = f - bf2f(h);
  hi = (short)h; lo = (short)f2bf(r);
}
__device__ __forceinline__ float sigm(float x){ return 1.f/(1.f+expf(-x)); }

// ---------------- conversion kernel (once per launch) ----------------
__global__ void conv_cat_split(u16* __restrict__ dhi, u16* __restrict__ dlo,
                               const float* __restrict__ s1, const float* __restrict__ s2,
                               int k1, int k2, int total8){
  int i = blockIdx.x*blockDim.x + threadIdx.x;
  if (i >= total8) return;
  int ktot = k1 + k2;
  long e = (long)i*8;
  int r = (int)(e / ktot); int k = (int)(e - (long)r*ktot);
  const float* s = (k < k1) ? (s1 + (size_t)r*k1 + k) : (s2 + (size_t)r*k2 + (k-k1));
  short8 oh, ol;
  #pragma unroll
  for (int q=0;q<8;++q){ short h,l; splitbf(s[q],h,l); oh[q]=h; ol[q]=l; }
  *(short8*)(dhi + e) = oh;
  *(short8*)(dlo + e) = ol;
}

// split 8 f32 (in regs) into hi/lo bf16 vectors
__device__ __forceinline__ void split8r(const float* x, short8& vh, short8& vl){
  #pragma unroll
  for (int q=0;q<8;++q){ short h,l; splitbf(x[q],h,l); vh[q]=h; vl[q]=l; }
}

// ---------------- LSTM1: barrier-free, LDS-free GEMM + cell update ----------------
// Block = 128 thr (2 waves). Wave = 16 rows x 16 jh-cols x 4 gates, K=1280.
// Per lane: A[row=n0+wv*16+(l&15)][k-chunk l>>4] loaded as 8 f32 from global
// (split hi/lo in regs); B[col=l&15][same chunk] as short8 hi + lo per gate.
// acc = Ah*Bh + Al*Bh + Ah*Bl. C layout: col=l&15 (jh), rows (l>>4)*4+r.
__global__ __launch_bounds__(128) void lstm1_k(
  const int* __restrict__ text, int t, int par,
  const float* __restrict__ emb,
  const float* __restrict__ ctx,
  float* __restrict__ h1b,
  float* __restrict__ c1,
  const u16* __restrict__ Whi, const u16* __restrict__ Wlo,
  const float* __restrict__ b_ih, const float* __restrict__ b_hh)
{
  const float* h1_old = h1b + (size_t)par*NB*HH;
  float* h1_new = h1b + (size_t)(par^1)*NB*HH;
  int b = blockIdx.x;
  int jt  = (b&7)*4 + ((b>>3)&3);     // XCD-grouped jh tiles (W slice L2-resident)
  int jh0 = jt*16;
  int n0  = (b>>5)*32;
  int tid = threadIdx.x, wv = tid>>6, l = tid&63;
  int col = l&15, kc = l>>4;          // B col / A row low bits, k-chunk
  int ofs = kc*8;

  int arow = n0 + wv*16 + col;
  const float* aemb = emb + (size_t)text[arow*TLEN + t]*HH;
  const float* actx = ctx + (size_t)arow*DV;
  const float* ah1  = h1_old + (size_t)arow*HH;

  const u16* pBh[4]; const u16* pBl[4];
  #pragma unroll
  for (int g=0; g<4; ++g){
    size_t r = (size_t)(g*512 + jh0 + col)*K1 + ofs;
    pBh[g] = Whi + r; pBl[g] = Wlo + r;
  }

  f32x4 acc[4];
  #pragma unroll
  for (int g=0;g<4;++g) acc[g] = (f32x4){0.f,0.f,0.f,0.f};

  // prefetch k0=0
  float xs[8]; short8 rbh[4], rbl[4];
  {
    const float* src = aemb;   // k0=0 -> emb region
    *(float4*)&xs[0] = *(const float4*)(src + ofs);
    *(float4*)&xs[4] = *(const float4*)(src + ofs + 4);
    #pragma unroll
    for (int g=0;g<4;++g){ rbh[g] = *(const short8*)(pBh[g]); rbl[g] = *(const short8*)(pBl[g]); }
  }

  for (int k0=0; k0<K1; k0+=32){
    float cxs[8];
    #pragma unroll
    for (int q=0;q<8;++q) cxs[q] = xs[q];
    short8 cbh[4], cbl[4];
    #pragma unroll
    for (int g=0;g<4;++g){ cbh[g]=rbh[g]; cbl[g]=rbl[g]; }
    // prefetch next iteration (independent loads, in flight under MFMA)
    int k0n = k0 + 32;
    if (k0n < K1){
      const float* src = (k0n<512)? (aemb + k0n) : (k0n<768)? (actx + (k0n-512)) : (ah1 + (k0n-768));
      *(float4*)&xs[0] = *(const float4*)(src + ofs);
      *(float4*)&xs[4] = *(const float4*)(src + ofs + 4);
      #pragma unroll
      for (int g=0;g<4;++g){ rbh[g] = *(const short8*)(pBh[g] + k0n); rbl[g] = *(const short8*)(pBl[g] + k0n); }
    }
    short8 avh, avl;
    split8r(cxs, avh, avl);
    #pragma unroll
    for (int g=0; g<4; ++g){
      acc[g] = __builtin_amdgcn_mfma_f32_16x16x32_bf16(avh, cbh[g], acc[g], 0,0,0);
      acc[g] = __builtin_amdgcn_mfma_f32_16x16x32_bf16(avl, cbh[g], acc[g], 0,0,0);
      acc[g] = __builtin_amdgcn_mfma_f32_16x16x32_bf16(avh, cbl[g], acc[g], 0,0,0);
    }
  }

  // epilogue: lane-local cell update. C rows = n0+wv*16+(l>>4)*4+r, col jh0+(l&15).
  int jh = jh0 + col;
  float bi  = b_ih[jh]      + b_hh[jh];
  float bff = b_ih[HH+jh]   + b_hh[HH+jh];
  float bg  = b_ih[2*HH+jh] + b_hh[2*HH+jh];
  float bo  = b_ih[3*HH+jh] + b_hh[3*HH+jh];
  int erow = n0 + wv*16 + kc*4;
  #pragma unroll
  for (int r=0;r<4;++r){
    size_t idx = (size_t)(erow+r)*HH + jh;
    float iv = sigm(acc[0][r]+bi);
    float fv = sigm(acc[1][r]+bff);
    float gv = tanhf(acc[2][r]+bg);
    float ov = sigm(acc[3][r]+bo);
    float cn = fv*c1[idx] + iv*gv;
    c1[idx] = cn;
    h1_new[idx] = ov*tanhf(cn);
  }
}

// ---------------- LSTM2: same structure, K=768, N=1024 ----------------
__global__ __launch_bounds__(128) void lstm2_k(
  int par,
  const float* __restrict__ h1b,
  float* __restrict__ h2b,
  float* __restrict__ c2,
  const u16* __restrict__ Whi, const u16* __restrict__ Wlo,
  const float* __restrict__ b_ih, const float* __restrict__ b_hh)
{
  const float* h1_cur = h1b + (size_t)(par^1)*NB*HH;
  const float* h2_old = h2b + (size_t)par*NB*DK;
  float* h2_new = h2b + (size_t)(par^1)*NB*DK;
  int b = blockIdx.x;
  int jt  = (b&7)*2 + ((b>>3)&1);
  int jh0 = jt*16;
  int n0  = (b>>4)*32;
  int tid = threadIdx.x, wv = tid>>6, l = tid&63;
  int col = l&15, kc = l>>4;
  int ofs = kc*8;

  int arow = n0 + wv*16 + col;
  const float* ah1 = h1_cur + (size_t)arow*HH;
  const float* ah2 = h2_old + (size_t)arow*DK;

  const u16* pBh[4]; const u16* pBl[4];
  #pragma unroll
  for (int g=0; g<4; ++g){
    size_t r = (size_t)(g*256 + jh0 + col)*K2 + ofs;
    pBh[g] = Whi + r; pBl[g] = Wlo + r;
  }

  f32x4 acc[4];
  #pragma unroll
  for (int g=0;g<4;++g) acc[g] = (f32x4){0.f,0.f,0.f,0.f};

  float xs[8]; short8 rbh[4], rbl[4];
  {
    const float* src = ah1;
    *(float4*)&xs[0] = *(const float4*)(src + ofs);
    *(float4*)&xs[4] = *(const float4*)(src + ofs + 4);
    #pragma unroll
    for (int g=0;g<4;++g){ rbh[g] = *(const short8*)(pBh[g]); rbl[g] = *(const short8*)(pBl[g]); }
  }

  for (int k0=0; k0<K2; k0+=32){
    float cxs[8];
    #pragma unroll
    for (int q=0;q<8;++q) cxs[q] = xs[q];
    short8 cbh[4], cbl[4];
    #pragma unroll
    for (int g=0;g<4;++g){ cbh[g]=rbh[g]; cbl[g]=rbl[g]; }
    int k0n = k0 + 32;
    if (k0n < K2){
      const float* src = (k0n<512)? (ah1 + k0n) : (ah2 + (k0n-512));
      *(float4*)&xs[0] = *(const float4*)(src + ofs);
      *(float4*)&xs[4] = *(const float4*)(src + ofs + 4);
      #pragma unroll
      for (int g=0;g<4;++g){ rbh[g] = *(const short8*)(pBh[g] + k0n); rbl[g] = *(const short8*)(pBl[g] + k0n); }
    }
    short8 avh, avl;
    split8r(cxs, avh, avl);
    #pragma unroll
    for (int g=0; g<4; ++g){
      acc[g] = __builtin_amdgcn_mfma_f32_16x16x32_bf16(avh, cbh[g], acc[g], 0,0,0);
      acc[g] = __builtin_amdgcn_mfma_f32_16x16x32_bf16(avl, cbh[g], acc[g], 0,0,0);
      acc[g] = __builtin_amdgcn_mfma_f32_16x16x32_bf16(avh, cbl[g], acc[g], 0,0,0);
    }
  }

  int jh = jh0 + col;
  float bi  = b_ih[jh]      + b_hh[jh];
  float bff = b_ih[DK+jh]   + b_hh[DK+jh];
  float bg  = b_ih[2*DK+jh] + b_hh[2*DK+jh];
  float bo  = b_ih[3*DK+jh] + b_hh[3*DK+jh];
  int erow = n0 + wv*16 + kc*4;
  #pragma unroll
  for (int r=0;r<4;++r){
    size_t idx = (size_t)(erow+r)*DK + jh;
    float iv = sigm(acc[0][r]+bi);
    float fv = sigm(acc[1][r]+bff);
    float gv = tanhf(acc[2][r]+bg);
    float ov = sigm(acc[3][r]+bo);
    float cn = fv*c2[idx] + iv*gv;
    c2[idx] = cn;
    h2_new[idx] = ov*tanhf(cn);
  }
}

// ---------------- attention + softmax + ctx + output projection (R6-proven) ----------------
__global__ __launch_bounds__(512) void attn_k(
  const float* __restrict__ keys, const float* __restrict__ vals,
  const int* __restrict__ lens,
  const float* __restrict__ h2b, int par,
  float* __restrict__ ctx,
  const float* __restrict__ Wout, const float* __restrict__ b_out,
  float* __restrict__ out, int t)
{
  __shared__ float h2s[DK];
  __shared__ float e_s[TE];
  __shared__ float ctx_s[DV];
  __shared__ float ctxp[8][DV];
  __shared__ float red_s[16];
  int n = blockIdx.x, tid = threadIdx.x;
  int wv = tid>>6, lane = tid&63;
  const float* h2cur = h2b + (size_t)(par^1)*NB*DK;
  int L = lens[n] >> 3;
  if (tid < DK) h2s[tid] = h2cur[n*DK + tid];
  __syncthreads();
  float qreg[32];
  {
    int off = (lane&7)*32;
    #pragma unroll
    for (int q=0;q<32;q+=4){
      float4 v4 = *(const float4*)&h2s[off+q];
      qreg[q]=v4.x; qreg[q+1]=v4.y; qreg[q+2]=v4.z; qreg[q+3]=v4.w;
    }
  }
  const float* kb = keys + (size_t)n*TE*DK;
  for (int r = wv*8 + (lane>>3); r < L; r += 64){
    const float* kr = kb + (size_t)r*DK + (lane&7)*32;
    float s = 0.f;
    #pragma unroll
    for (int q=0;q<32;q+=4){
      float4 kv = *(const float4*)(kr + q);
      s += kv.x*qreg[q] + kv.y*qreg[q+1] + kv.z*qreg[q+2] + kv.w*qreg[q+3];
    }
    s += __shfl_xor(s,1); s += __shfl_xor(s,2); s += __shfl_xor(s,4);
    if ((lane&7)==0) e_s[r] = s;
  }
  __syncthreads();
  float v = (tid < L) ? e_s[tid] : -1e30f;
  float m = v;
  #pragma unroll
  for (int o=1;o<64;o<<=1) m = fmaxf(m, __shfl_xor(m,o));
  if (lane==0) red_s[wv] = m;
  __syncthreads();
  m = red_s[0];
  #pragma unroll
  for (int q=1;q<8;++q) m = fmaxf(m, red_s[q]);
  float p = (tid < L) ? expf(v-m) : 0.f;
  float sm = p;
  #pragma unroll
  for (int o=1;o<64;o<<=1) sm += __shfl_xor(sm,o);
  if (lane==0) red_s[8+wv] = sm;
  __syncthreads();
  sm = red_s[8];
  #pragma unroll
  for (int q=1;q<8;++q) sm += red_s[8+q];
  e_s[tid] = p * (1.f/sm);
  __syncthreads();
  float4 cacc = {0.f,0.f,0.f,0.f};
  const float* vpb = vals + (size_t)n*TE*DV + lane*4;
  for (int r = wv; r < L; r += 8){
    float a = e_s[r];
    float4 vv4 = *(const float4*)(vpb + (size_t)r*DV);
    cacc.x += a*vv4.x; cacc.y += a*vv4.y; cacc.z += a*vv4.z; cacc.w += a*vv4.w;
  }
  *(float4*)&ctxp[wv][lane*4] = cacc;
  __syncthreads();
  if (tid < DV){
    float cv = 0.f;
    #pragma unroll
    for (int q=0;q<8;++q) cv += ctxp[q][tid];
    ctx_s[tid] = cv;
    ctx[(size_t)n*DV + tid] = cv;
  }
  __syncthreads();
  #pragma unroll
  for (int vb2=0; vb2<2; ++vb2){
    int vvv = vb2*32 + (tid>>4);
    if (vvv < NV){
      int kbase = (tid&15)*32;
      float s = 0.f;
      #pragma unroll
      for (int q=0;q<32;q+=4){
        float4 w4 = *(const float4*)(Wout + (size_t)vvv*512 + kbase + q);
        int k = kbase + q;
        const float* xs = (k < DK)? &h2s[k] : &ctx_s[k-DK];
        s += w4.x*xs[0] + w4.y*xs[1] + w4.z*xs[2] + w4.w*xs[3];
      }
      s += __shfl_xor(s,1); s += __shfl_xor(s,2); s += __shfl_xor(s,4); s += __shfl_xor(s,8);
      if ((tid&15)==0) out[((size_t)n*STEPS + t)*NV + vvv] = s + b_out[vvv];
    }
  }
}

// ---------------- host ----------------
extern "C" void kernel_launch(void* const* d_in, const int* in_sizes, int n_in,
                              void* d_out, int out_size, void* d_ws, size_t ws_size,
                              hipStream_t stream)
{
  const float* enc_key = (const float*)d_in[0];
  const float* enc_val = (const float*)d_in[1];
  const int*   text    = (const int*)d_in[2];
  const int*   lens    = (const int*)d_in[3];
  const float* emb     = (const float*)d_in[5];
  const float* W_ih1   = (const float*)d_in[6];
  const float* W_hh1   = (const float*)d_in[7];
  const float* b_ih1   = (const float*)d_in[8];
  const float* b_hh1   = (const float*)d_in[9];
  const float* W_ih2   = (const float*)d_in[10];
  const float* W_hh2   = (const float*)d_in[11];
  const float* b_ih2   = (const float*)d_in[12];
  const float* b_hh2   = (const float*)d_in[13];
  const float* W_out   = (const float*)d_in[14];
  const float* b_out   = (const float*)d_in[15];
  float* out = (float*)d_out;

  char* ws = (char*)d_ws;
  size_t off = 0;
  auto alloc = [&](size_t bytes)->char*{
    char* p = ws + off; off = (off + bytes + 255) & ~(size_t)255; return p;
  };

  u16* Wc1h = (u16*)alloc((size_t)2048*K1*2);
  u16* Wc1l = (u16*)alloc((size_t)2048*K1*2);
  u16* Wc2h = (u16*)alloc((size_t)1024*K2*2);
  u16* Wc2l = (u16*)alloc((size_t)1024*K2*2);
  float* h1b = (float*)alloc((size_t)2*NB*HH*4);
  float* h2b = (float*)alloc((size_t)2*NB*DK*4);
  float* ctx = (float*)alloc((size_t)NB*DV*4);
  float* c1  = (float*)alloc((size_t)NB*HH*4);
  float* c2  = (float*)alloc((size_t)NB*DK*4);

  // zero recurrent state (contiguous block h1b..c2)
  size_t zbytes = (char*)c2 + (size_t)NB*DK*4 - (char*)h1b;
  (void)hipMemsetAsync(h1b, 0, zbytes, stream);

  {
    int t8 = 2048*K1/8;
    conv_cat_split<<<(t8+255)/256, 256, 0, stream>>>(Wc1h, Wc1l, W_ih1, W_hh1, 768, 512, t8);
  }
  {
    int t8 = 1024*K2/8;
    conv_cat_split<<<(t8+255)/256, 256, 0, stream>>>(Wc2h, Wc2l, W_ih2, W_hh2, 512, 256, t8);
  }

  for (int t=0; t<STEPS; ++t){
    int par = t&1;
    lstm1_k<<<256, 128, 0, stream>>>(text, t, par, emb, ctx, h1b, c1, Wc1h, Wc1l, b_ih1, b_hh1);
    lstm2_k<<<128, 128, 0, stream>>>(par, h1b, h2b, c2, Wc2h, Wc2l, b_ih2, b_hh2);
    attn_k<<<256, 512, 0, stream>>>(enc_key, enc_val, lens, h2b, par, ctx, W_out, b_out, out, t);
  }
}

// Round 12
// 24506.721 us; speedup vs baseline: 2.7934x; 1.0459x over previous
//
#include <hip/hip_runtime.h>

typedef unsigned short u16;
typedef __attribute__((ext_vector_type(8))) short short8;
typedef __attribute__((ext_vector_type(4))) float f32x4;

#define NB 256      // batch
#define TE 512      // encoder T
#define DK 256      // key dim
#define DV 256      // value dim
#define HH 512      // hidden
#define NV 35       // vocab
#define STEPS 300
#define TLEN 301
#define K1 1280     // LSTM1 inner dim: emb(512) + ctx(256) + h1(512)
#define K2 768      // LSTM2 inner dim: h1(512) + h2(256)

__device__ __forceinline__ float bf2f(u16 u){ return __uint_as_float(((unsigned)u)<<16); }
__device__ __forceinline__ u16 f2bf(float f){
  unsigned u = __float_as_uint(f);
  u += 0x7fffu + ((u>>16)&1u);   // RNE
  return (u16)(u>>16);
}
__device__ __forceinline__ void splitbf(float f, short& hi, short& lo){
  u16 h = f2bf(f);
  float r = f - bf2f(h);
  hi = (short)h; lo = (short)f2bf(r);
}
__device__ __forceinline__ float sigm(float x){ return 1.f/(1.f+expf(-x)); }

// ---------------- conversion kernel (once per launch) ----------------
__global__ void conv_cat_split(u16* __restrict__ dhi, u16* __restrict__ dlo,
                               const float* __restrict__ s1, const float* __restrict__ s2,
                               int k1, int k2, int total8){
  int i = blockIdx.x*blockDim.x + threadIdx.x;
  if (i >= total8) return;
  int ktot = k1 + k2;
  long e = (long)i*8;
  int r = (int)(e / ktot); int k = (int)(e - (long)r*ktot);
  const float* s = (k < k1) ? (s1 + (size_t)r*k1 + k) : (s2 + (size_t)r*k2 + (k-k1));
  short8 oh, ol;
  #pragma unroll
  for (int q=0;q<8;++q){ short h,l; splitbf(s[q],h,l); oh[q]=h; ol[q]=l; }
  *(short8*)(dhi + e) = oh;
  *(short8*)(dlo + e) = ol;
}

__device__ __forceinline__ void split8r(const float* x, short8& vh, short8& vl){
  #pragma unroll
  for (int q=0;q<8;++q){ short h,l; splitbf(x[q],h,l); vh[q]=h; vl[q]=l; }
}

// ---------------- LSTM1: K-split 8-wave GEMM + cell update ----------------
// Block = 512 thr (8 waves) = 2 n-halves x 4 K-quarters. Wave: 16 rows x 16 jh
// x 4 gates over K/4=320 (10 iters). No barriers in K-loop; one LDS reduce.
__global__ __launch_bounds__(512) void lstm1_k(
  const int* __restrict__ text, int t, int par,
  const float* __restrict__ emb,
  const float* __restrict__ ctx,
  float* __restrict__ h1b,
  float* __restrict__ c1,
  const u16* __restrict__ Whi, const u16* __restrict__ Wlo,
  const float* __restrict__ b_ih, const float* __restrict__ b_hh)
{
  __shared__ __align__(16) float accS[4][4][2][64][4];   // [gate][kq][nh][lane][reg] 32KB
  const float* h1_old = h1b + (size_t)par*NB*HH;
  float* h1_new = h1b + (size_t)(par^1)*NB*HH;
  int b = blockIdx.x;
  int jt  = (b&7)*4 + ((b>>3)&3);     // XCD-grouped jh tiles (W slice L2-resident)
  int jh0 = jt*16;
  int n0  = (b>>5)*32;
  int tid = threadIdx.x, w = tid>>6, l = tid&63;
  int nh = w&1, kq = w>>1;
  int kbase = kq*(K1/4);
  int col = l&15, kc = l>>4, ofs = kc*8;

  int arow = n0 + nh*16 + col;
  const float* aemb = emb + (size_t)text[arow*TLEN + t]*HH;
  const float* actx = ctx + (size_t)arow*DV;
  const float* ah1  = h1_old + (size_t)arow*HH;

  const u16* pBh[4]; const u16* pBl[4];
  #pragma unroll
  for (int g=0; g<4; ++g){
    size_t r = (size_t)(g*512 + jh0 + col)*K1 + kbase + ofs;
    pBh[g] = Whi + r; pBl[g] = Wlo + r;
  }

  f32x4 acc[4];
  #pragma unroll
  for (int g=0;g<4;++g) acc[g] = (f32x4){0.f,0.f,0.f,0.f};

  // prefetch first chunk of this wave's K range
  float xs[8]; short8 rbh[4], rbl[4];
  {
    int k = kbase;
    const float* src = (k<512)? (aemb+k) : (k<768)? (actx+(k-512)) : (ah1+(k-768));
    *(float4*)&xs[0] = *(const float4*)(src + ofs);
    *(float4*)&xs[4] = *(const float4*)(src + ofs + 4);
    #pragma unroll
    for (int g=0;g<4;++g){ rbh[g] = *(const short8*)(pBh[g]); rbl[g] = *(const short8*)(pBl[g]); }
  }

  for (int k0=0; k0<K1/4; k0+=32){
    float cxs[8];
    #pragma unroll
    for (int q=0;q<8;++q) cxs[q] = xs[q];
    short8 cbh[4], cbl[4];
    #pragma unroll
    for (int g=0;g<4;++g){ cbh[g]=rbh[g]; cbl[g]=rbl[g]; }
    int k0n = k0 + 32;
    if (k0n < K1/4){
      int k = kbase + k0n;
      const float* src = (k<512)? (aemb+k) : (k<768)? (actx+(k-512)) : (ah1+(k-768));
      *(float4*)&xs[0] = *(const float4*)(src + ofs);
      *(float4*)&xs[4] = *(const float4*)(src + ofs + 4);
      #pragma unroll
      for (int g=0;g<4;++g){ rbh[g] = *(const short8*)(pBh[g] + k0n); rbl[g] = *(const short8*)(pBl[g] + k0n); }
    }
    short8 avh, avl;
    split8r(cxs, avh, avl);
    #pragma unroll
    for (int g=0; g<4; ++g){
      acc[g] = __builtin_amdgcn_mfma_f32_16x16x32_bf16(avh, cbh[g], acc[g], 0,0,0);
      acc[g] = __builtin_amdgcn_mfma_f32_16x16x32_bf16(avl, cbh[g], acc[g], 0,0,0);
      acc[g] = __builtin_amdgcn_mfma_f32_16x16x32_bf16(avh, cbl[g], acc[g], 0,0,0);
    }
  }

  #pragma unroll
  for (int g=0;g<4;++g) *(f32x4*)&accS[g][kq][nh][l][0] = acc[g];
  __syncthreads();

  // epilogue: thread = one cell. en 0..31 (row in tile-pair), ej 0..15 (jh col)
  int en = tid>>4, ej = tid&15;
  int nhe = en>>4, r = en&15;
  int lane_e = ((r>>2)<<4) | ej, reg = r&3;
  float gv4[4];
  #pragma unroll
  for (int g=0;g<4;++g){
    gv4[g] = accS[g][0][nhe][lane_e][reg] + accS[g][1][nhe][lane_e][reg]
           + accS[g][2][nhe][lane_e][reg] + accS[g][3][nhe][lane_e][reg];
  }
  int jh = jh0 + ej;
  float bi  = b_ih[jh]      + b_hh[jh];
  float bff = b_ih[HH+jh]   + b_hh[HH+jh];
  float bg  = b_ih[2*HH+jh] + b_hh[2*HH+jh];
  float bo  = b_ih[3*HH+jh] + b_hh[3*HH+jh];
  size_t idx = (size_t)(n0+en)*HH + jh;
  float iv = sigm(gv4[0]+bi);
  float fv = sigm(gv4[1]+bff);
  float gg = tanhf(gv4[2]+bg);
  float ov = sigm(gv4[3]+bo);
  float cn = fv*c1[idx] + iv*gg;
  c1[idx] = cn;
  h1_new[idx] = ov*tanhf(cn);
}

// ---------------- LSTM2: K-split 8-wave, K=768 (192/wave, 6 iters) ----------------
__global__ __launch_bounds__(512) void lstm2_k(
  int par,
  const float* __restrict__ h1b,
  float* __restrict__ h2b,
  float* __restrict__ c2,
  const u16* __restrict__ Whi, const u16* __restrict__ Wlo,
  const float* __restrict__ b_ih, const float* __restrict__ b_hh)
{
  __shared__ __align__(16) float accS[4][4][2][64][4];
  const float* h1_cur = h1b + (size_t)(par^1)*NB*HH;
  const float* h2_old = h2b + (size_t)par*NB*DK;
  float* h2_new = h2b + (size_t)(par^1)*NB*DK;
  int b = blockIdx.x;
  int jt  = (b&7)*2 + ((b>>3)&1);
  int jh0 = jt*16;
  int n0  = (b>>4)*32;
  int tid = threadIdx.x, w = tid>>6, l = tid&63;
  int nh = w&1, kq = w>>1;
  int kbase = kq*(K2/4);
  int col = l&15, kc = l>>4, ofs = kc*8;

  int arow = n0 + nh*16 + col;
  const float* ah1 = h1_cur + (size_t)arow*HH;
  const float* ah2 = h2_old + (size_t)arow*DK;

  const u16* pBh[4]; const u16* pBl[4];
  #pragma unroll
  for (int g=0; g<4; ++g){
    size_t r = (size_t)(g*256 + jh0 + col)*K2 + kbase + ofs;
    pBh[g] = Whi + r; pBl[g] = Wlo + r;
  }

  f32x4 acc[4];
  #pragma unroll
  for (int g=0;g<4;++g) acc[g] = (f32x4){0.f,0.f,0.f,0.f};

  float xs[8]; short8 rbh[4], rbl[4];
  {
    int k = kbase;
    const float* src = (k<512)? (ah1+k) : (ah2+(k-512));
    *(float4*)&xs[0] = *(const float4*)(src + ofs);
    *(float4*)&xs[4] = *(const float4*)(src + ofs + 4);
    #pragma unroll
    for (int g=0;g<4;++g){ rbh[g] = *(const short8*)(pBh[g]); rbl[g] = *(const short8*)(pBl[g]); }
  }

  for (int k0=0; k0<K2/4; k0+=32){
    float cxs[8];
    #pragma unroll
    for (int q=0;q<8;++q) cxs[q] = xs[q];
    short8 cbh[4], cbl[4];
    #pragma unroll
    for (int g=0;g<4;++g){ cbh[g]=rbh[g]; cbl[g]=rbl[g]; }
    int k0n = k0 + 32;
    if (k0n < K2/4){
      int k = kbase + k0n;
      const float* src = (k<512)? (ah1+k) : (ah2+(k-512));
      *(float4*)&xs[0] = *(const float4*)(src + ofs);
      *(float4*)&xs[4] = *(const float4*)(src + ofs + 4);
      #pragma unroll
      for (int g=0;g<4;++g){ rbh[g] = *(const short8*)(pBh[g] + k0n); rbl[g] = *(const short8*)(pBl[g] + k0n); }
    }
    short8 avh, avl;
    split8r(cxs, avh, avl);
    #pragma unroll
    for (int g=0; g<4; ++g){
      acc[g] = __builtin_amdgcn_mfma_f32_16x16x32_bf16(avh, cbh[g], acc[g], 0,0,0);
      acc[g] = __builtin_amdgcn_mfma_f32_16x16x32_bf16(avl, cbh[g], acc[g], 0,0,0);
      acc[g] = __builtin_amdgcn_mfma_f32_16x16x32_bf16(avh, cbl[g], acc[g], 0,0,0);
    }
  }

  #pragma unroll
  for (int g=0;g<4;++g) *(f32x4*)&accS[g][kq][nh][l][0] = acc[g];
  __syncthreads();

  int en = tid>>4, ej = tid&15;
  int nhe = en>>4, r = en&15;
  int lane_e = ((r>>2)<<4) | ej, reg = r&3;
  float gv4[4];
  #pragma unroll
  for (int g=0;g<4;++g){
    gv4[g] = accS[g][0][nhe][lane_e][reg] + accS[g][1][nhe][lane_e][reg]
           + accS[g][2][nhe][lane_e][reg] + accS[g][3][nhe][lane_e][reg];
  }
  int jh = jh0 + ej;
  float bi  = b_ih[jh]      + b_hh[jh];
  float bff = b_ih[DK+jh]   + b_hh[DK+jh];
  float bg  = b_ih[2*DK+jh] + b_hh[2*DK+jh];
  float bo  = b_ih[3*DK+jh] + b_hh[3*DK+jh];
  size_t idx = (size_t)(n0+en)*DK + jh;
  float iv = sigm(gv4[0]+bi);
  float fv = sigm(gv4[1]+bff);
  float gg = tanhf(gv4[2]+bg);
  float ov = sigm(gv4[3]+bo);
  float cn = fv*c2[idx] + iv*gg;
  c2[idx] = cn;
  h2_new[idx] = ov*tanhf(cn);
}

// ---------------- attention + softmax + ctx + output projection (R6-proven) ----------------
__global__ __launch_bounds__(512) void attn_k(
  const float* __restrict__ keys, const float* __restrict__ vals,
  const int* __restrict__ lens,
  const float* __restrict__ h2b, int par,
  float* __restrict__ ctx,
  const float* __restrict__ Wout, const float* __restrict__ b_out,
  float* __restrict__ out, int t)
{
  __shared__ float h2s[DK];
  __shared__ float e_s[TE];
  __shared__ float ctx_s[DV];
  __shared__ float ctxp[8][DV];
  __shared__ float red_s[16];
  int n = blockIdx.x, tid = threadIdx.x;
  int wv = tid>>6, lane = tid&63;
  const float* h2cur = h2b + (size_t)(par^1)*NB*DK;
  int L = lens[n] >> 3;
  if (tid < DK) h2s[tid] = h2cur[n*DK + tid];
  __syncthreads();
  float qreg[32];
  {
    int off = (lane&7)*32;
    #pragma unroll
    for (int q=0;q<32;q+=4){
      float4 v4 = *(const float4*)&h2s[off+q];
      qreg[q]=v4.x; qreg[q+1]=v4.y; qreg[q+2]=v4.z; qreg[q+3]=v4.w;
    }
  }
  const float* kb = keys + (size_t)n*TE*DK;
  for (int r = wv*8 + (lane>>3); r < L; r += 64){
    const float* kr = kb + (size_t)r*DK + (lane&7)*32;
    float s = 0.f;
    #pragma unroll
    for (int q=0;q<32;q+=4){
      float4 kv = *(const float4*)(kr + q);
      s += kv.x*qreg[q] + kv.y*qreg[q+1] + kv.z*qreg[q+2] + kv.w*qreg[q+3];
    }
    s += __shfl_xor(s,1); s += __shfl_xor(s,2); s += __shfl_xor(s,4);
    if ((lane&7)==0) e_s[r] = s;
  }
  __syncthreads();
  float v = (tid < L) ? e_s[tid] : -1e30f;
  float m = v;
  #pragma unroll
  for (int o=1;o<64;o<<=1) m = fmaxf(m, __shfl_xor(m,o));
  if (lane==0) red_s[wv] = m;
  __syncthreads();
  m = red_s[0];
  #pragma unroll
  for (int q=1;q<8;++q) m = fmaxf(m, red_s[q]);
  float p = (tid < L) ? expf(v-m) : 0.f;
  float sm = p;
  #pragma unroll
  for (int o=1;o<64;o<<=1) sm += __shfl_xor(sm,o);
  if (lane==0) red_s[8+wv] = sm;
  __syncthreads();
  sm = red_s[8];
  #pragma unroll
  for (int q=1;q<8;++q) sm += red_s[8+q];
  e_s[tid] = p * (1.f/sm);
  __syncthreads();
  float4 cacc = {0.f,0.f,0.f,0.f};
  const float* vpb = vals + (size_t)n*TE*DV + lane*4;
  for (int r = wv; r < L; r += 8){
    float a = e_s[r];
    float4 vv4 = *(const float4*)(vpb + (size_t)r*DV);
    cacc.x += a*vv4.x; cacc.y += a*vv4.y; cacc.z += a*vv4.z; cacc.w += a*vv4.w;
  }
  *(float4*)&ctxp[wv][lane*4] = cacc;
  __syncthreads();
  if (tid < DV){
    float cv = 0.f;
    #pragma unroll
    for (int q=0;q<8;++q) cv += ctxp[q][tid];
    ctx_s[tid] = cv;
    ctx[(size_t)n*DV + tid] = cv;
  }
  __syncthreads();
  #pragma unroll
  for (int vb2=0; vb2<2; ++vb2){
    int vvv = vb2*32 + (tid>>4);
    if (vvv < NV){
      int kbase = (tid&15)*32;
      float s = 0.f;
      #pragma unroll
      for (int q=0;q<32;q+=4){
        float4 w4 = *(const float4*)(Wout + (size_t)vvv*512 + kbase + q);
        int k = kbase + q;
        const float* xs = (k < DK)? &h2s[k] : &ctx_s[k-DK];
        s += w4.x*xs[0] + w4.y*xs[1] + w4.z*xs[2] + w4.w*xs[3];
      }
      s += __shfl_xor(s,1); s += __shfl_xor(s,2); s += __shfl_xor(s,4); s += __shfl_xor(s,8);
      if ((tid&15)==0) out[((size_t)n*STEPS + t)*NV + vvv] = s + b_out[vvv];
    }
  }
}

// ---------------- host ----------------
extern "C" void kernel_launch(void* const* d_in, const int* in_sizes, int n_in,
                              void* d_out, int out_size, void* d_ws, size_t ws_size,
                              hipStream_t stream)
{
  const float* enc_key = (const float*)d_in[0];
  const float* enc_val = (const float*)d_in[1];
  const int*   text    = (const int*)d_in[2];
  const int*   lens    = (const int*)d_in[3];
  const float* emb     = (const float*)d_in[5];
  const float* W_ih1   = (const float*)d_in[6];
  const float* W_hh1   = (const float*)d_in[7];
  const float* b_ih1   = (const float*)d_in[8];
  const float* b_hh1   = (const float*)d_in[9];
  const float* W_ih2   = (const float*)d_in[10];
  const float* W_hh2   = (const float*)d_in[11];
  const float* b_ih2   = (const float*)d_in[12];
  const float* b_hh2   = (const float*)d_in[13];
  const float* W_out   = (const float*)d_in[14];
  const float* b_out   = (const float*)d_in[15];
  float* out = (float*)d_out;

  char* ws = (char*)d_ws;
  size_t off = 0;
  auto alloc = [&](size_t bytes)->char*{
    char* p = ws + off; off = (off + bytes + 255) & ~(size_t)255; return p;
  };

  u16* Wc1h = (u16*)alloc((size_t)2048*K1*2);
  u16* Wc1l = (u16*)alloc((size_t)2048*K1*2);
  u16* Wc2h = (u16*)alloc((size_t)1024*K2*2);
  u16* Wc2l = (u16*)alloc((size_t)1024*K2*2);
  float* h1b = (float*)alloc((size_t)2*NB*HH*4);
  float* h2b = (float*)alloc((size_t)2*NB*DK*4);
  float* ctx = (float*)alloc((size_t)NB*DV*4);
  float* c1  = (float*)alloc((size_t)NB*HH*4);
  float* c2  = (float*)alloc((size_t)NB*DK*4);

  // zero recurrent state (contiguous block h1b..c2)
  size_t zbytes = (char*)c2 + (size_t)NB*DK*4 - (char*)h1b;
  (void)hipMemsetAsync(h1b, 0, zbytes, stream);

  {
    int t8 = 2048*K1/8;
    conv_cat_split<<<(t8+255)/256, 256, 0, stream>>>(Wc1h, Wc1l, W_ih1, W_hh1, 768, 512, t8);
  }
  {
    int t8 = 1024*K2/8;
    conv_cat_split<<<(t8+255)/256, 256, 0, stream>>>(Wc2h, Wc2l, W_ih2, W_hh2, 512, 256, t8);
  }

  for (int t=0; t<STEPS; ++t){
    int par = t&1;
    lstm1_k<<<256, 512, 0, stream>>>(text, t, par, emb, ctx, h1b, c1, Wc1h, Wc1l, b_ih1, b_hh1);
    lstm2_k<<<128, 512, 0, stream>>>(par, h1b, h2b, c2, Wc2h, Wc2l, b_ih2, b_hh2);
    attn_k<<<256, 512, 0, stream>>>(enc_key, enc_val, lens, h2b, par, ctx, W_out, b_out, out, t);
  }
}